// Round 4
// baseline (169.034 us; speedup 1.0000x reference)
//
#include <hip/hip_runtime.h>

// Shapes fixed by the reference's setup_inputs
#define BS    64        // B*S = 4*16
#define DDIM  512       // attention dim (K)
#define NV    32000     // vocab
#define TD    18        // tree depth
#define INNER 31999     // V-1 internal nodes (N)

typedef __attribute__((ext_vector_type(8))) short short8;
typedef __attribute__((ext_vector_type(4))) float floatx4;

__device__ __forceinline__ float bf16_to_f32(unsigned short u) {
    union { unsigned int i; float f; } v; v.i = ((unsigned int)u) << 16; return v.f;
}
__device__ __forceinline__ unsigned short f32_to_bf16(float f) {
    union { float f; unsigned int i; } v; v.f = f;
    unsigned int r = v.i + 0x7FFFu + ((v.i >> 16) & 1u);   // RNE
    return (unsigned short)(r >> 16);
}
__device__ __forceinline__ short8 cvt8(float4 a, float4 b) {
    short8 s;
    s[0] = (short)f32_to_bf16(a.x); s[1] = (short)f32_to_bf16(a.y);
    s[2] = (short)f32_to_bf16(a.z); s[3] = (short)f32_to_bf16(a.w);
    s[4] = (short)f32_to_bf16(b.x); s[5] = (short)f32_to_bf16(b.y);
    s[6] = (short)f32_to_bf16(b.z); s[7] = (short)f32_to_bf16(b.w);
    return s;
}

// --------------------------------------------------------------------------
// x[m][n] = att[m,:]·weight[n,:], bf16 MFMA 16x16x32, both operands
// converted fp32->bf16 in-register (att is 128 KB and L2/L1-hot after the
// first touch, so no prep pass and no attb roundtrip).
// ROUND-3 POST-MORTEM: LDS/DMA staging regressed (+12 us) — 16-B DMA ops
// against the ~63-outstanding vmcnt cap ceiling at ~2.3 TB/s and the
// compiler's vmcnt(0) barrier drain serializes the prefetch. Direct per-lane
// float4 loads at 16 waves/CU keep >BDP bytes in flight -> BW-bound.
// Concurrency doubled vs round 2: 1000 blocks, wave = 16n x 32m (m-split
// by 2; the 2x weight re-read is same-block, L1/L2-absorbed).
// Epilogue: lp = log sigmoid(x) = -softplus(-x); lm = lp - x; pack both
// bf16 into u32; store TRANSPOSED pairsT[n][m] (gather's bs-lane layout).
// C/D map (m89): col = lane&15, row = (lane>>4)*4 + reg.
// --------------------------------------------------------------------------
__global__ __launch_bounds__(256) void gemm_logsig(
    const float* __restrict__ att,               // [64][512] fp32
    const float* __restrict__ weight,            // [INNER][512] fp32
    unsigned int* __restrict__ pairsT)           // [NV][64] u32 (lm<<16)|lp
{
    const int tid  = threadIdx.x;
    const int lane = tid & 63;
    const int wave = tid >> 6;                   // 0..3
    const int nsub = wave & 1;                   // 16-n group
    const int msub = wave >> 1;                  // 32-m group
    const int l15  = lane & 15;
    const int quad = lane >> 4;
    const int B0   = blockIdx.x * 32;            // grid 1000 -> n-range 32

    floatx4 acc[2];
    acc[0] = (floatx4){0.f, 0.f, 0.f, 0.f};
    acc[1] = (floatx4){0.f, 0.f, 0.f, 0.f};

    int brow = B0 + nsub * 16 + l15;
    if (brow > INNER - 1) brow = INNER - 1;      // clamp; stores guarded
    const float* bbase = weight + (size_t)brow * DDIM + quad * 8;
    const float* a0    = att + (size_t)(msub * 32 + l15) * DDIM + quad * 8;
    const float* a1    = a0 + 16 * DDIM;

#pragma unroll 4
    for (int k0 = 0; k0 < DDIM; k0 += 32) {
        float4 b0 = *(const float4*)(bbase + k0);
        float4 b1 = *(const float4*)(bbase + k0 + 4);
        float4 x0 = *(const float4*)(a0 + k0);
        float4 x1 = *(const float4*)(a0 + k0 + 4);
        float4 y0 = *(const float4*)(a1 + k0);
        float4 y1 = *(const float4*)(a1 + k0 + 4);
        short8 bfrag = cvt8(b0, b1);
        short8 af0   = cvt8(x0, x1);
        short8 af1   = cvt8(y0, y1);
        acc[0] = __builtin_amdgcn_mfma_f32_16x16x32_bf16(af0, bfrag, acc[0], 0, 0, 0);
        acc[1] = __builtin_amdgcn_mfma_f32_16x16x32_bf16(af1, bfrag, acc[1], 0, 0, 0);
    }

    const int n = B0 + nsub * 16 + l15;
    if (n < INNER) {
        unsigned int* dst = pairsT + ((size_t)n << 6) + msub * 32 + quad * 4;
#pragma unroll
        for (int mt = 0; mt < 2; ++mt) {
            unsigned int wds[4];
#pragma unroll
            for (int r = 0; r < 4; ++r) {
                // m = msub*32 + mt*16 + quad*4 + r  (row of C = bs index)
                float x = acc[mt][r];
                float lp = -(fmaxf(-x, 0.f) + __logf(1.f + __expf(-fabsf(x))));
                float lm = lp - x;
                wds[r] = (unsigned int)f32_to_bf16(lp)
                       | ((unsigned int)f32_to_bf16(lm) << 16);
            }
            uint4 wv; wv.x = wds[0]; wv.y = wds[1]; wv.z = wds[2]; wv.w = wds[3];
            *(uint4*)(dst + mt * 16) = wv;       // pairsT[n][msub*32+mt*16+quad*4..+3]
        }
    }
}

// --------------------------------------------------------------------------
// out[bs][v] = sum_t half(pairsT[e>>1][bs], e&1),  e = 2*idx[v*18+t]+signbit.
// LANE = bs (tree path identical for all 64 bs rows):
//  - this block's 576 idx/sign entries staged once into LDS (coalesced),
//  - index reads from LDS are wave-uniform broadcasts,
//  - pair gather is a fully coalesced 256-B read pairsT[n][0..63] from the
//    L2/L3-resident 8.2 MB pairsT buffer.
// Small LDS tile transposes per-lane sums so the out write is float4-
// coalesced along v. Grid 1000 x 256 (32 v per block, 8 per wave).
// --------------------------------------------------------------------------
__global__ __launch_bounds__(256) void gather_bs(
    const unsigned int* __restrict__ pairsT,     // [NV][64] u32
    const int* __restrict__ idx,                 // int32/int64 [576000]
    const unsigned int* __restrict__ signbits,   // fp32 path_sign raw bits
    float* __restrict__ out)                     // [64][NV] fp32
{
    __shared__ unsigned int eLDS[576];           // e = 2*idx + signbit
    __shared__ float tile[32][65];               // +1 pad: conflict-free transpose
    const int tid   = threadIdx.x;
    const int lane  = tid & 63;                  // = bs
    const int wave  = tid >> 6;
    const int vbase = blockIdx.x * 32;

    // i64 iff first 8 odd u32 words are all zero (P_err ~ (1/32000)^8)
    const unsigned int* w = (const unsigned int*)idx;
    bool i64 = true;
#pragma unroll
    for (int j = 1; j < 16; j += 2) i64 &= (w[j] == 0u);

    for (int q = tid; q < 576; q += 256) {
        int g = vbase * TD + q;                  // max 575,999 — in bounds
        int val = i64 ? idx[2 * g] : idx[g];
        eLDS[q] = ((unsigned int)val << 1) | (signbits[g] >> 31);
    }
    __syncthreads();

#pragma unroll
    for (int i = 0; i < 8; ++i) {
        const int vloc = wave * 8 + i;
        const unsigned int* col = eLDS + vloc * TD;
        float s0 = 0.f, s1 = 0.f;
#pragma unroll
        for (int t = 0; t < TD; t += 2) {
            unsigned int e0 = col[t];            // wave-uniform LDS broadcast
            unsigned int e1 = col[t + 1];
            unsigned int p0 = pairsT[((size_t)(e0 >> 1) << 6) + lane];
            unsigned int p1 = pairsT[((size_t)(e1 >> 1) << 6) + lane];
            unsigned short h0 = (e0 & 1u) ? (unsigned short)(p0 >> 16)
                                          : (unsigned short)(p0 & 0xFFFFu);
            unsigned short h1 = (e1 & 1u) ? (unsigned short)(p1 >> 16)
                                          : (unsigned short)(p1 & 0xFFFFu);
            s0 += bf16_to_f32(h0);
            s1 += bf16_to_f32(h1);
        }
        tile[vloc][lane] = s0 + s1;
    }
    __syncthreads();

    const int bs  = threadIdx.x >> 2;            // 0..63
    const int seg = threadIdx.x & 3;             // 0..3 (8 v each)
    float4 r0, r1;
    r0.x = tile[seg * 8 + 0][bs]; r0.y = tile[seg * 8 + 1][bs];
    r0.z = tile[seg * 8 + 2][bs]; r0.w = tile[seg * 8 + 3][bs];
    r1.x = tile[seg * 8 + 4][bs]; r1.y = tile[seg * 8 + 5][bs];
    r1.z = tile[seg * 8 + 6][bs]; r1.w = tile[seg * 8 + 7][bs];
    float4* dst = (float4*)(out + (size_t)bs * NV + vbase + seg * 8);
    dst[0] = r0; dst[1] = r1;
}

extern "C" void kernel_launch(void* const* d_in, const int* in_sizes, int n_in,
                              void* d_out, int out_size, void* d_ws, size_t ws_size,
                              hipStream_t stream)
{
    const float*        att    = (const float*)d_in[0];        // fp32 [4,16,512]
    const float*        weight = (const float*)d_in[1];        // fp32 [31999,512]
    const int*          pidx   = (const int*)d_in[2];          // int32/int64 [576000]
    const unsigned int* psign  = (const unsigned int*)d_in[3]; // fp32 bits [576000]
    // d_in[4] path_bias (redundant: bias=(1-sign)/2), d_in[5..6] scalars
    float* out = (float*)d_out;                                // fp32 [64][32000]

    // workspace: pairsT only — 8,192,000 B
    unsigned int* pairsT = (unsigned int*)d_ws;

    gemm_logsig<<<1000, 256, 0, stream>>>(att, weight, pairsT);
    gather_bs<<<1000, 256, 0, stream>>>(pairsT, pidx, psign, out);
}

// Round 5
// 144.462 us; speedup vs baseline: 1.1701x; 1.1701x over previous
//
#include <hip/hip_runtime.h>

// Shapes fixed by the reference's setup_inputs
#define BS    64        // B*S = 4*16
#define DDIM  512       // attention dim (K)
#define NV    32000     // vocab
#define TD    18        // tree depth
#define INNER 31999     // V-1 internal nodes (N)

typedef __attribute__((ext_vector_type(8))) short short8;
typedef __attribute__((ext_vector_type(4))) float floatx4;

__device__ __forceinline__ float bf16_to_f32(unsigned short u) {
    union { unsigned int i; float f; } v; v.i = ((unsigned int)u) << 16; return v.f;
}
__device__ __forceinline__ unsigned short f32_to_bf16(float f) {
    union { float f; unsigned int i; } v; v.f = f;
    unsigned int r = v.i + 0x7FFFu + ((v.i >> 16) & 1u);   // RNE
    return (unsigned short)(r >> 16);
}
__device__ __forceinline__ short8 cvt8(float4 a, float4 b) {
    short8 s;
    s[0] = (short)f32_to_bf16(a.x); s[1] = (short)f32_to_bf16(a.y);
    s[2] = (short)f32_to_bf16(a.z); s[3] = (short)f32_to_bf16(a.w);
    s[4] = (short)f32_to_bf16(b.x); s[5] = (short)f32_to_bf16(b.y);
    s[6] = (short)f32_to_bf16(b.z); s[7] = (short)f32_to_bf16(b.w);
    return s;
}

// --------------------------------------------------------------------------
// prep_att: att fp32 -> bf16 (8192 float4). Tiny (32 blocks). Pre-converting
// A removes 2 of 3 cvt8 from every GEMM k-step and halves A-load bytes.
// --------------------------------------------------------------------------
__global__ __launch_bounds__(256) void prep_att(
    const float4* __restrict__ att, ushort4* __restrict__ attb)
{
    int i = blockIdx.x * 256 + threadIdx.x;    // 0..8191
    float4 a = att[i];
    ushort4 r;
    r.x = f32_to_bf16(a.x); r.y = f32_to_bf16(a.y);
    r.z = f32_to_bf16(a.z); r.w = f32_to_bf16(a.w);
    attb[i] = r;
}

// --------------------------------------------------------------------------
// x[m][n] = att[m,:]·weight[n,:], bf16 MFMA 16x16x32.
// ROUND-4 POST-MORTEM: VGPR=64 -> compiler serialized the unrolled loads
// into ~16 sequential HBM waits/wave (HBM 10%, VALU 15%, Mfma 1.4% — all
// idle). FIX: structural MLP — two named 8xfloat4 register buffers for the
// B (weight) stream; 16 loads issued before any use, LOAD/COMPUTE pipeline
// keeps >=8 loads (8-16 KB/wave) in flight at all times. 1000 blocks
// (~4/CU, 16 waves/CU) -> ~32 MB chip-wide in flight >> BDP -> BW-bound.
// Wave = 16n x 32m (2 MFMA/k-step); weight n-rows unique per nsub pair,
// msub duplication absorbed by L1/L2.
// Epilogue: lp = log sigmoid(x) = -softplus(-x); lm = lp - x; pack bf16
// pair into u32; store TRANSPOSED pairsT[n][m] (gather's bs-lane layout).
// C/D map (m89): col = lane&15, row = (lane>>4)*4 + reg.
// --------------------------------------------------------------------------
#define LOADB(BUF, c)                                                        \
    {                                                                        \
        _Pragma("unroll")                                                    \
        for (int s = 0; s < 4; ++s) {                                        \
            BUF[2*s]   = *(const float4*)(bbase + (c)*128 + s*32);           \
            BUF[2*s+1] = *(const float4*)(bbase + (c)*128 + s*32 + 4);       \
        }                                                                    \
    }
#define COMPUTE(BUF, c)                                                      \
    {                                                                        \
        _Pragma("unroll")                                                    \
        for (int s = 0; s < 4; ++s) {                                        \
            short8 bfrag = cvt8(BUF[2*s], BUF[2*s+1]);                       \
            const int k0 = (c)*128 + s*32;                                   \
            short8 af0 = *(const short8*)(a0 + k0);                          \
            short8 af1 = *(const short8*)(a1 + k0);                          \
            acc0 = __builtin_amdgcn_mfma_f32_16x16x32_bf16(af0, bfrag, acc0, 0, 0, 0); \
            acc1 = __builtin_amdgcn_mfma_f32_16x16x32_bf16(af1, bfrag, acc1, 0, 0, 0); \
        }                                                                    \
    }

__global__ __launch_bounds__(256) void gemm_logsig(
    const unsigned short* __restrict__ attb,     // [64][512] bf16
    const float* __restrict__ weight,            // [INNER][512] fp32
    unsigned int* __restrict__ pairsT)           // [NV][64] u32 (lm<<16)|lp
{
    const int tid  = threadIdx.x;
    const int lane = tid & 63;
    const int wave = tid >> 6;                   // 0..3
    const int nsub = wave & 1;                   // 16-n group
    const int msub = wave >> 1;                  // 32-m group
    const int l15  = lane & 15;
    const int quad = lane >> 4;
    const int B0   = blockIdx.x * 32;            // grid 1000 -> n-range 32

    floatx4 acc0 = (floatx4){0.f, 0.f, 0.f, 0.f};
    floatx4 acc1 = (floatx4){0.f, 0.f, 0.f, 0.f};

    int brow = B0 + nsub * 16 + l15;
    if (brow > INNER - 1) brow = INNER - 1;      // clamp; stores guarded
    const float*          bbase = weight + (size_t)brow * DDIM + quad * 8;
    const unsigned short* a0    = attb + (size_t)(msub * 32 + l15) * DDIM + quad * 8;
    const unsigned short* a1    = a0 + 16 * DDIM;

    float4 bufA[8], bufB[8];                     // 2 x 32 VGPR B-stage
    LOADB(bufA, 0);                              // 16 loads in flight before
    LOADB(bufB, 1);                              //   any consumer
    COMPUTE(bufA, 0);                            // waits only on bufA's 8
    LOADB(bufA, 2);
    COMPUTE(bufB, 1);
    LOADB(bufB, 3);
    COMPUTE(bufA, 2);
    COMPUTE(bufB, 3);

    const int n = B0 + nsub * 16 + l15;
    if (n < INNER) {
        unsigned int* dst = pairsT + ((size_t)n << 6) + msub * 32 + quad * 4;
        floatx4 accs[2] = {acc0, acc1};
#pragma unroll
        for (int mt = 0; mt < 2; ++mt) {
            unsigned int wds[4];
#pragma unroll
            for (int r = 0; r < 4; ++r) {
                // m = msub*32 + mt*16 + quad*4 + r  (row of C = bs index)
                float x = accs[mt][r];
                float lp = -(fmaxf(-x, 0.f) + __logf(1.f + __expf(-fabsf(x))));
                float lm = lp - x;
                wds[r] = (unsigned int)f32_to_bf16(lp)
                       | ((unsigned int)f32_to_bf16(lm) << 16);
            }
            uint4 wv; wv.x = wds[0]; wv.y = wds[1]; wv.z = wds[2]; wv.w = wds[3];
            *(uint4*)(dst + mt * 16) = wv;       // pairsT[n][msub*32+mt*16+quad*4..+3]
        }
    }
}

// --------------------------------------------------------------------------
// out[bs][v] = sum_t half(pairsT[e>>1][bs], e&1),  e = 2*idx[v*18+t]+signbit.
// LANE = bs (tree path identical for all 64 bs rows); pair gather is a
// fully coalesced 256-B read pairsT[n][0..63].
// ROUND-4 POST-MORTEM: old t-loop had only 2 independent loads at a time ->
// 72 sequential ~600-cyc waits per wave (~18 us). FIX: per v-PAIR, read all
// 36 e-values from LDS first, then issue all 36 gathers concurrently, then
// reduce — serial chain cut 18x. Grid 1000 x 256 (32 v/block, 8 v/wave).
// Small LDS tile transposes per-lane sums so the out write is float4-
// coalesced along v.
// --------------------------------------------------------------------------
__global__ __launch_bounds__(256) void gather_bs(
    const unsigned int* __restrict__ pairsT,     // [NV][64] u32
    const int* __restrict__ idx,                 // int32/int64 [576000]
    const unsigned int* __restrict__ signbits,   // fp32 path_sign raw bits
    float* __restrict__ out)                     // [64][NV] fp32
{
    __shared__ unsigned int eLDS[576];           // e = 2*idx + signbit
    __shared__ float tile[32][65];               // +1 pad: conflict-free transpose
    const int tid   = threadIdx.x;
    const int lane  = tid & 63;                  // = bs
    const int wave  = tid >> 6;
    const int vbase = blockIdx.x * 32;

    // i64 iff first 8 odd u32 words are all zero (P_err ~ (1/32000)^8)
    const unsigned int* w = (const unsigned int*)idx;
    bool i64 = true;
#pragma unroll
    for (int j = 1; j < 16; j += 2) i64 &= (w[j] == 0u);

    for (int q = tid; q < 576; q += 256) {
        int g = vbase * TD + q;                  // max 575,999 — in bounds
        int val = i64 ? idx[2 * g] : idx[g];
        eLDS[q] = ((unsigned int)val << 1) | (signbits[g] >> 31);
    }
    __syncthreads();

#pragma unroll
    for (int i = 0; i < 8; i += 2) {
        const int vA = wave * 8 + i;
        const int vB = vA + 1;
        const unsigned int* cA = eLDS + vA * TD;
        const unsigned int* cB = eLDS + vB * TD;
        unsigned int eA[TD], eB[TD], pA[TD], pB[TD];
#pragma unroll
        for (int t = 0; t < TD; ++t) { eA[t] = cA[t]; eB[t] = cB[t]; }
#pragma unroll
        for (int t = 0; t < TD; ++t) {           // 36 loads, all independent
            pA[t] = pairsT[((size_t)(eA[t] >> 1) << 6) + lane];
            pB[t] = pairsT[((size_t)(eB[t] >> 1) << 6) + lane];
        }
        float sA = 0.f, sB = 0.f;
#pragma unroll
        for (int t = 0; t < TD; ++t) {
            sA += bf16_to_f32((unsigned short)(pA[t] >> ((eA[t] & 1u) << 4)));
            sB += bf16_to_f32((unsigned short)(pB[t] >> ((eB[t] & 1u) << 4)));
        }
        tile[vA][lane] = sA;
        tile[vB][lane] = sB;
    }
    __syncthreads();

    const int bs  = threadIdx.x >> 2;            // 0..63
    const int seg = threadIdx.x & 3;             // 0..3 (8 v each)
    float4 r0, r1;
    r0.x = tile[seg * 8 + 0][bs]; r0.y = tile[seg * 8 + 1][bs];
    r0.z = tile[seg * 8 + 2][bs]; r0.w = tile[seg * 8 + 3][bs];
    r1.x = tile[seg * 8 + 4][bs]; r1.y = tile[seg * 8 + 5][bs];
    r1.z = tile[seg * 8 + 6][bs]; r1.w = tile[seg * 8 + 7][bs];
    float4* dst = (float4*)(out + (size_t)bs * NV + vbase + seg * 8);
    dst[0] = r0; dst[1] = r1;
}

extern "C" void kernel_launch(void* const* d_in, const int* in_sizes, int n_in,
                              void* d_out, int out_size, void* d_ws, size_t ws_size,
                              hipStream_t stream)
{
    const float*        att    = (const float*)d_in[0];        // fp32 [4,16,512]
    const float*        weight = (const float*)d_in[1];        // fp32 [31999,512]
    const int*          pidx   = (const int*)d_in[2];          // int32/int64 [576000]
    const unsigned int* psign  = (const unsigned int*)d_in[3]; // fp32 bits [576000]
    // d_in[4] path_bias (redundant: bias=(1-sign)/2), d_in[5..6] scalars
    float* out = (float*)d_out;                                // fp32 [64][32000]

    // workspace: 8,257,536 B total (16B-aligned offsets)
    char* ws = (char*)d_ws;
    unsigned int* pairsT = (unsigned int*)ws;                  // 8,192,000 B
    ushort4*      attb   = (ushort4*)(ws + 8192000);           //    65,536 B

    prep_att<<<32, 256, 0, stream>>>((const float4*)att, attb);
    gemm_logsig<<<1000, 256, 0, stream>>>((const unsigned short*)attb, weight, pairsT);
    gather_bs<<<1000, 256, 0, stream>>>(pairsT, pidx, psign, out);
}